// Round 2
// baseline (55.707 us; speedup 1.0000x reference)
//
#include <hip/hip_runtime.h>

// Fixed-shape problem
#define NBATCH 4
#define NPTS   8192
#define MTGT   8192
#define BN     (NBATCH*NPTS)      // 32768 sources
#define TPB    256
#define SPT    8                  // sources per thread
#define SPB    (TPB*SPT)          // 2048 sources per block
#define NXBLK  (BN/SPB)           // 16
#define CHUNK  256                // targets staged per block
#define NCHUNK (MTGT/CHUNK)       // 32

typedef float f32x2 __attribute__((ext_vector_type(2)));

// Monotone float->uint key (preserves order under unsigned compare)
__device__ __forceinline__ unsigned f2key(float x) {
    unsigned u = __float_as_uint(x);
    return (u & 0x80000000u) ? ~u : (u | 0x80000000u);
}
__device__ __forceinline__ float key2f(unsigned k) {
    return __uint_as_float((k & 0x80000000u) ? (k ^ 0x80000000u) : ~k);
}

__global__ __launch_bounds__(256) void init_kernel(unsigned* __restrict__ wsmin,
                                                   float* __restrict__ out) {
    int i = blockIdx.x * 256 + threadIdx.x;
    wsmin[i] = 0xFFFFFFFFu;   // +inf in key space
    if (i == 0) out[0] = 0.f;
}

// Per source point, partial min over one chunk of targets of d' = ||t||^2 - 2 s.t
__global__ __launch_bounds__(TPB) void nn_min_kernel(const float* __restrict__ src,
                                                     const float* __restrict__ tgt,
                                                     unsigned* __restrict__ wsmin) {
    __shared__ float  raw[CHUNK * 3];
    __shared__ float4 lt[CHUNK];     // (x, y, z, ||t||^2); invalid -> 1e30

    const int tid = threadIdx.x;
    const int bx  = blockIdx.x;
    const int c   = blockIdx.y;
    const int b   = bx / (NPTS / SPB);   // 4 x-blocks per batch

    // ---- stage CHUNK targets ----
    const float4* tv = reinterpret_cast<const float4*>(
        tgt + ((size_t)b * MTGT + (size_t)c * CHUNK) * 3);
    if (tid < CHUNK * 3 / 4) reinterpret_cast<float4*>(raw)[tid] = tv[tid];
    __syncthreads();
    {
        float x = raw[3 * tid], y = raw[3 * tid + 1], z = raw[3 * tid + 2];
        float tsq = fmaf(x, x, fmaf(y, y, z * z));
        bool valid = (x != 0.f) || (y != 0.f) || (z != 0.f);
        lt[tid] = make_float4(x, y, z, valid ? tsq : 1e30f);
    }
    __syncthreads();

    // ---- load 8 source points (contiguous 96B per thread) ----
    const int s0 = bx * SPB + tid * SPT;
    const float4* sv = reinterpret_cast<const float4*>(src + (size_t)s0 * 3);
    float4 q0 = sv[0], q1 = sv[1], q2 = sv[2], q3 = sv[3], q4 = sv[4], q5 = sv[5];
    float sxs[8] = {q0.x, q0.w, q1.z, q2.y, q3.x, q3.w, q4.z, q5.y};
    float sys[8] = {q0.y, q1.x, q1.w, q2.z, q3.y, q4.x, q4.w, q5.z};
    float szs[8] = {q0.z, q1.y, q2.x, q2.w, q3.z, q4.y, q5.x, q5.w};

    f32x2 ax[4], ay[4], az[4], bm[4];
#pragma unroll
    for (int p = 0; p < 4; ++p) {
        ax[p] = f32x2{-2.f * sxs[2 * p], -2.f * sxs[2 * p + 1]};
        ay[p] = f32x2{-2.f * sys[2 * p], -2.f * sys[2 * p + 1]};
        az[p] = f32x2{-2.f * szs[2 * p], -2.f * szs[2 * p + 1]};
        bm[p] = f32x2{3e38f, 3e38f};
    }

    // ---- inner loop: per target, 1 broadcast LDS read feeds 8 sources ----
#pragma unroll 4
    for (int m = 0; m < CHUNK; ++m) {
        float4 t = lt[m];
        f32x2 tx = f32x2{t.x, t.x};
        f32x2 ty = f32x2{t.y, t.y};
        f32x2 tz = f32x2{t.z, t.z};
        f32x2 tw = f32x2{t.w, t.w};
#pragma unroll
        for (int p = 0; p < 4; ++p) {
            f32x2 d = __builtin_elementwise_fma(ax[p], tx,
                      __builtin_elementwise_fma(ay[p], ty,
                      __builtin_elementwise_fma(az[p], tz, tw)));
            bm[p].x = fminf(bm[p].x, d.x);
            bm[p].y = fminf(bm[p].y, d.y);
        }
    }

#pragma unroll
    for (int p = 0; p < 4; ++p) {
        atomicMin(&wsmin[s0 + 2 * p + 0], f2key(bm[p].x));
        atomicMin(&wsmin[s0 + 2 * p + 1], f2key(bm[p].y));
    }
}

// Per-batch weighted mean of exact squared distances; atomicAdd of batch mean/4.
__global__ __launch_bounds__(256) void reduce_kernel(const float* __restrict__ src,
                                                     const unsigned* __restrict__ wsmin,
                                                     float* __restrict__ out) {
    const int b = blockIdx.x;
    const int tid = threadIdx.x;
    double sum = 0.0, cnt = 0.0;
    for (int n = tid; n < NPTS; n += 256) {
        int gid = b * NPTS + n;
        float sx = src[(size_t)gid * 3 + 0];
        float sy = src[(size_t)gid * 3 + 1];
        float sz = src[(size_t)gid * 3 + 2];
        bool valid = (sx != 0.f) || (sy != 0.f) || (sz != 0.f);
        float ssq = fmaf(sx, sx, fmaf(sy, sy, sz * sz));
        float sq = fmaxf(0.f, ssq + key2f(wsmin[gid]));
        if (valid) { sum += (double)sq; cnt += 1.0; }
    }
    __shared__ double sh[512];
    sh[tid] = sum; sh[256 + tid] = cnt;
    __syncthreads();
    for (int s = 128; s > 0; s >>= 1) {
        if (tid < s) { sh[tid] += sh[tid + s]; sh[256 + tid] += sh[256 + tid + s]; }
        __syncthreads();
    }
    if (tid == 0) {
        double c = sh[256] > 1.0 ? sh[256] : 1.0;
        atomicAdd(out, (float)(sh[0] / (3.0 * c) / (double)NBATCH));
    }
}

extern "C" void kernel_launch(void* const* d_in, const int* in_sizes, int n_in,
                              void* d_out, int out_size, void* d_ws, size_t ws_size,
                              hipStream_t stream) {
    const float* src = (const float*)d_in[0];
    const float* tgt = (const float*)d_in[1];
    float* out = (float*)d_out;
    unsigned* wsmin = (unsigned*)d_ws;

    init_kernel<<<dim3(BN / 256), dim3(256), 0, stream>>>(wsmin, out);

    dim3 g1(NXBLK, NCHUNK);
    nn_min_kernel<<<g1, dim3(TPB), 0, stream>>>(src, tgt, wsmin);

    reduce_kernel<<<dim3(NBATCH), dim3(256), 0, stream>>>(src, wsmin, out);
}

// Round 3
// 41.656 us; speedup vs baseline: 1.3373x; 1.3373x over previous
//
#include <hip/hip_runtime.h>

// Fixed-shape problem
#define NBATCH 4
#define NPTS   8192
#define MTGT   8192
#define BN     (NBATCH*NPTS)      // 32768 sources
#define TPB    256
#define SPT    8                  // sources per thread (keeps LDS off critical path)
#define SPB    (TPB*SPT)          // 2048 sources per block
#define NXBLK  (BN/SPB)           // 16
#define CHUNK  128                // targets staged per block
#define NCHUNK (MTGT/CHUNK)       // 64  -> grid 16x64 = 1024 blocks (4/CU)

typedef float f32x2 __attribute__((ext_vector_type(2)));

__device__ __forceinline__ f32x2 pkfma(f32x2 a, f32x2 b, f32x2 c) {
    return __builtin_elementwise_fma(a, b, c);
}
__device__ __forceinline__ f32x2 pkmin(f32x2 a, f32x2 b) {
    return __builtin_elementwise_min(a, b);
}

// ---------------- main path (atomic-free, partial-min matrix in ws) ----------------

// wspart[c*BN + s] = min over targets in chunk c of (||t||^2 - 2 s.t)
__global__ __launch_bounds__(TPB) void nn_min_kernel(const float* __restrict__ src,
                                                     const float* __restrict__ tgt,
                                                     float* __restrict__ wspart) {
    __shared__ float  raw[CHUNK * 3];
    __shared__ float4 lt[CHUNK];     // (x,y,z,||t||^2); invalid -> 1e30

    const int tid = threadIdx.x;
    const int bx  = blockIdx.x;
    const int c   = blockIdx.y;
    const int b   = bx / (NPTS / SPB);   // 4 x-blocks per batch

    const float4* tv = reinterpret_cast<const float4*>(
        tgt + ((size_t)b * MTGT + (size_t)c * CHUNK) * 3);
    if (tid < CHUNK * 3 / 4) reinterpret_cast<float4*>(raw)[tid] = tv[tid];
    __syncthreads();
    if (tid < CHUNK) {
        float x = raw[3 * tid], y = raw[3 * tid + 1], z = raw[3 * tid + 2];
        float tsq = fmaf(x, x, fmaf(y, y, z * z));
        bool valid = (x != 0.f) || (y != 0.f) || (z != 0.f);
        lt[tid] = make_float4(x, y, z, valid ? tsq : 1e30f);
    }
    __syncthreads();

    const int s0 = bx * SPB + tid * SPT;
    const float4* sv = reinterpret_cast<const float4*>(src + (size_t)s0 * 3);
    float4 q0 = sv[0], q1 = sv[1], q2 = sv[2], q3 = sv[3], q4 = sv[4], q5 = sv[5];
    float sxs[8] = {q0.x, q0.w, q1.z, q2.y, q3.x, q3.w, q4.z, q5.y};
    float sys[8] = {q0.y, q1.x, q1.w, q2.z, q3.y, q4.x, q4.w, q5.z};
    float szs[8] = {q0.z, q1.y, q2.x, q2.w, q3.z, q4.y, q5.x, q5.w};

    f32x2 ax[4], ay[4], az[4], bmE[4], bmO[4];
#pragma unroll
    for (int p = 0; p < 4; ++p) {
        ax[p] = f32x2{-2.f * sxs[2 * p], -2.f * sxs[2 * p + 1]};
        ay[p] = f32x2{-2.f * sys[2 * p], -2.f * sys[2 * p + 1]};
        az[p] = f32x2{-2.f * szs[2 * p], -2.f * szs[2 * p + 1]};
        bmE[p] = f32x2{3e38f, 3e38f};
        bmO[p] = f32x2{3e38f, 3e38f};
    }

    // 1 broadcast ds_read_b128 feeds 8 sources; even/odd accumulators break min chain
#pragma unroll 2
    for (int m = 0; m < CHUNK; m += 2) {
        float4 t0 = lt[m], t1 = lt[m + 1];
        f32x2 t0x = {t0.x, t0.x}, t0y = {t0.y, t0.y}, t0z = {t0.z, t0.z}, t0w = {t0.w, t0.w};
        f32x2 t1x = {t1.x, t1.x}, t1y = {t1.y, t1.y}, t1z = {t1.z, t1.z}, t1w = {t1.w, t1.w};
#pragma unroll
        for (int p = 0; p < 4; ++p) {
            bmE[p] = pkmin(bmE[p], pkfma(ax[p], t0x, pkfma(ay[p], t0y, pkfma(az[p], t0z, t0w))));
            bmO[p] = pkmin(bmO[p], pkfma(ax[p], t1x, pkfma(ay[p], t1y, pkfma(az[p], t1z, t1w))));
        }
    }

    f32x2 r0 = pkmin(bmE[0], bmO[0]);
    f32x2 r1 = pkmin(bmE[1], bmO[1]);
    f32x2 r2 = pkmin(bmE[2], bmO[2]);
    f32x2 r3 = pkmin(bmE[3], bmO[3]);
    float4* wp = reinterpret_cast<float4*>(wspart + (size_t)c * BN + s0);
    wp[0] = make_float4(r0.x, r0.y, r1.x, r1.y);
    wp[1] = make_float4(r2.x, r2.y, r3.x, r3.y);
}

// 128 blocks: (batch, slice-of-256-sources). Deterministic double partials.
__global__ __launch_bounds__(256) void reduce_kernel(const float* __restrict__ src,
                                                     const float* __restrict__ wspart,
                                                     double* __restrict__ partials) {
    const int blk = blockIdx.x;
    const int b = blk >> 5, slice = blk & 31;
    const int tid = threadIdx.x;
    const int gid = b * NPTS + slice * 256 + tid;

    float m = 3e38f;
#pragma unroll 4
    for (int c = 0; c < NCHUNK; ++c) m = fminf(m, wspart[(size_t)c * BN + gid]);

    float sx = src[(size_t)gid * 3 + 0];
    float sy = src[(size_t)gid * 3 + 1];
    float sz = src[(size_t)gid * 3 + 2];
    bool valid = (sx != 0.f) || (sy != 0.f) || (sz != 0.f);
    float ssq = fmaf(sx, sx, fmaf(sy, sy, sz * sz));
    float sq = fmaxf(0.f, ssq + m);

    __shared__ double sh[512];
    sh[tid] = valid ? (double)sq : 0.0;
    sh[256 + tid] = valid ? 1.0 : 0.0;
    __syncthreads();
    for (int s = 128; s > 0; s >>= 1) {
        if (tid < s) { sh[tid] += sh[tid + s]; sh[256 + tid] += sh[256 + tid + s]; }
        __syncthreads();
    }
    if (tid == 0) { partials[2 * blk] = sh[0]; partials[2 * blk + 1] = sh[256]; }
}

__global__ void final_kernel(const double* __restrict__ partials, float* __restrict__ out) {
    __shared__ double bm[4];
    int t = threadIdx.x;
    if (t < 4) {
        double s = 0.0, c = 0.0;
        for (int i = 0; i < 32; ++i) { s += partials[2 * (t * 32 + i)]; c += partials[2 * (t * 32 + i) + 1]; }
        if (c < 1.0) c = 1.0;
        bm[t] = s / (3.0 * c);
    }
    __syncthreads();
    if (t == 0) out[0] = (float)((bm[0] + bm[1] + bm[2] + bm[3]) * 0.25);
}

// ---------------- fallback path (tiny ws): stale-check atomics ----------------

__device__ __forceinline__ unsigned f2key(float x) {
    unsigned u = __float_as_uint(x);
    return (u & 0x80000000u) ? ~u : (u | 0x80000000u);
}
__device__ __forceinline__ float key2f(unsigned k) {
    return __uint_as_float((k & 0x80000000u) ? (k ^ 0x80000000u) : ~k);
}

__global__ __launch_bounds__(256) void init_kernel(unsigned* __restrict__ wsmin,
                                                   float* __restrict__ out) {
    int i = blockIdx.x * 256 + threadIdx.x;
    wsmin[i] = 0xFFFFFFFFu;
    if (i == 0) out[0] = 0.f;
}

__global__ __launch_bounds__(TPB) void nn_min_atomic(const float* __restrict__ src,
                                                     const float* __restrict__ tgt,
                                                     unsigned* __restrict__ wsmin) {
    __shared__ float  raw[CHUNK * 3];
    __shared__ float4 lt[CHUNK];
    const int tid = threadIdx.x, bx = blockIdx.x, c = blockIdx.y;
    const int b = bx / (NPTS / SPB);
    const float4* tv = reinterpret_cast<const float4*>(
        tgt + ((size_t)b * MTGT + (size_t)c * CHUNK) * 3);
    if (tid < CHUNK * 3 / 4) reinterpret_cast<float4*>(raw)[tid] = tv[tid];
    __syncthreads();
    if (tid < CHUNK) {
        float x = raw[3 * tid], y = raw[3 * tid + 1], z = raw[3 * tid + 2];
        float tsq = fmaf(x, x, fmaf(y, y, z * z));
        bool valid = (x != 0.f) || (y != 0.f) || (z != 0.f);
        lt[tid] = make_float4(x, y, z, valid ? tsq : 1e30f);
    }
    __syncthreads();
    const int s0 = bx * SPB + tid * SPT;
    const float4* sv = reinterpret_cast<const float4*>(src + (size_t)s0 * 3);
    float4 q0 = sv[0], q1 = sv[1], q2 = sv[2], q3 = sv[3], q4 = sv[4], q5 = sv[5];
    float sxs[8] = {q0.x, q0.w, q1.z, q2.y, q3.x, q3.w, q4.z, q5.y};
    float sys[8] = {q0.y, q1.x, q1.w, q2.z, q3.y, q4.x, q4.w, q5.z};
    float szs[8] = {q0.z, q1.y, q2.x, q2.w, q3.z, q4.y, q5.x, q5.w};
    f32x2 ax[4], ay[4], az[4], bmE[4], bmO[4];
#pragma unroll
    for (int p = 0; p < 4; ++p) {
        ax[p] = f32x2{-2.f * sxs[2 * p], -2.f * sxs[2 * p + 1]};
        ay[p] = f32x2{-2.f * sys[2 * p], -2.f * sys[2 * p + 1]};
        az[p] = f32x2{-2.f * szs[2 * p], -2.f * szs[2 * p + 1]};
        bmE[p] = f32x2{3e38f, 3e38f};
        bmO[p] = f32x2{3e38f, 3e38f};
    }
#pragma unroll 2
    for (int m = 0; m < CHUNK; m += 2) {
        float4 t0 = lt[m], t1 = lt[m + 1];
        f32x2 t0x = {t0.x, t0.x}, t0y = {t0.y, t0.y}, t0z = {t0.z, t0.z}, t0w = {t0.w, t0.w};
        f32x2 t1x = {t1.x, t1.x}, t1y = {t1.y, t1.y}, t1z = {t1.z, t1.z}, t1w = {t1.w, t1.w};
#pragma unroll
        for (int p = 0; p < 4; ++p) {
            bmE[p] = pkmin(bmE[p], pkfma(ax[p], t0x, pkfma(ay[p], t0y, pkfma(az[p], t0z, t0w))));
            bmO[p] = pkmin(bmO[p], pkfma(ax[p], t1x, pkfma(ay[p], t1y, pkfma(az[p], t1z, t1w))));
        }
    }
    volatile unsigned* wv = wsmin;
#pragma unroll
    for (int p = 0; p < 4; ++p) {
        f32x2 r = pkmin(bmE[p], bmO[p]);
        unsigned k0 = f2key(r.x), k1 = f2key(r.y);
        // stale value only ever >= true current (monotone decrease) -> safe skip
        if (k0 < wv[s0 + 2 * p + 0]) atomicMin(&wsmin[s0 + 2 * p + 0], k0);
        if (k1 < wv[s0 + 2 * p + 1]) atomicMin(&wsmin[s0 + 2 * p + 1], k1);
    }
}

__global__ __launch_bounds__(256) void reduce_atomic(const float* __restrict__ src,
                                                     const unsigned* __restrict__ wsmin,
                                                     float* __restrict__ out) {
    const int b = blockIdx.x;
    const int tid = threadIdx.x;
    double sum = 0.0, cnt = 0.0;
    for (int n = tid; n < NPTS; n += 256) {
        int gid = b * NPTS + n;
        float sx = src[(size_t)gid * 3 + 0];
        float sy = src[(size_t)gid * 3 + 1];
        float sz = src[(size_t)gid * 3 + 2];
        bool valid = (sx != 0.f) || (sy != 0.f) || (sz != 0.f);
        float ssq = fmaf(sx, sx, fmaf(sy, sy, sz * sz));
        float sq = fmaxf(0.f, ssq + key2f(wsmin[gid]));
        if (valid) { sum += (double)sq; cnt += 1.0; }
    }
    __shared__ double sh[512];
    sh[tid] = sum; sh[256 + tid] = cnt;
    __syncthreads();
    for (int s = 128; s > 0; s >>= 1) {
        if (tid < s) { sh[tid] += sh[tid + s]; sh[256 + tid] += sh[256 + tid + s]; }
        __syncthreads();
    }
    if (tid == 0) {
        double c = sh[256] > 1.0 ? sh[256] : 1.0;
        atomicAdd(out, (float)(sh[0] / (3.0 * c) / (double)NBATCH));
    }
}

// ---------------- host ----------------

extern "C" void kernel_launch(void* const* d_in, const int* in_sizes, int n_in,
                              void* d_out, int out_size, void* d_ws, size_t ws_size,
                              hipStream_t stream) {
    const float* src = (const float*)d_in[0];
    const float* tgt = (const float*)d_in[1];
    float* out = (float*)d_out;

    const size_t need = (size_t)NCHUNK * BN * sizeof(float) + 4096;
    if (ws_size >= need) {
        float* wspart = (float*)d_ws;
        double* partials = (double*)((char*)d_ws + (size_t)NCHUNK * BN * sizeof(float));
        nn_min_kernel<<<dim3(NXBLK, NCHUNK), dim3(TPB), 0, stream>>>(src, tgt, wspart);
        reduce_kernel<<<dim3(128), dim3(256), 0, stream>>>(src, wspart, partials);
        final_kernel<<<dim3(1), dim3(64), 0, stream>>>(partials, out);
    } else {
        unsigned* wsmin = (unsigned*)d_ws;
        init_kernel<<<dim3(BN / 256), dim3(256), 0, stream>>>(wsmin, out);
        nn_min_atomic<<<dim3(NXBLK, NCHUNK), dim3(TPB), 0, stream>>>(src, tgt, wsmin);
        reduce_atomic<<<dim3(NBATCH), dim3(256), 0, stream>>>(src, wsmin, out);
    }
}